// Round 2
// baseline (265.439 us; speedup 1.0000x reference)
//
#include <hip/hip_runtime.h>

#define LOG2E 1.4426950408889634f

constexpr int Dn = 128;
constexpr int Nn = 16384;
constexpr int Kn = 64;
constexpr int Bn = 16;

typedef __attribute__((ext_vector_type(16))) float f32x16;

// Prep: folds mu-normalize, exp(-log_sigma), factor -2, k-constant and log2e.
// Layout v3: wout[((k>>2)*64 + dh)*4 + (k&3)] — the 4-k slice of wave-group
// (k>>2) at a given dh is 64 contiguous bytes (one s_load_dwordx16).
__global__ __launch_bounds__(64) void gmm_prep(const float* __restrict__ mu,
                                               const float* __restrict__ log_sigma,
                                               const float* __restrict__ log_alpha,
                                               float4* __restrict__ wout,
                                               float* __restrict__ cout) {
    const int k = blockIdx.x;
    const int l = threadIdx.x;        // l == dh
    const int d0 = 2 * l;
    float m0 = mu[k * Dn + d0];
    float m1 = mu[k * Dn + d0 + 1];
    float s0 = log_sigma[k * Dn + d0];
    float s1 = log_sigma[k * Dn + d0 + 1];
    float nrm2 = m0 * m0 + m1 * m1;
    float lss = s0 + s1;
    #pragma unroll
    for (int off = 32; off > 0; off >>= 1) {
        nrm2 += __shfl_xor(nrm2, off);
        lss  += __shfl_xor(lss, off);
    }
    const float inv_nrm = 1.0f / fmaxf(sqrtf(nrm2), 1e-12f);
    const float mn0 = m0 * inv_nrm, mn1 = m1 * inv_nrm;
    const float si0 = expf(-s0), si1 = expf(-s1);
    float mt = mn0 * mn0 * si0 + mn1 * mn1 * si1;
    #pragma unroll
    for (int off = 32; off > 0; off >>= 1) mt += __shfl_xor(mt, off);
    wout[((k >> 2) * 64 + l) * 4 + (k & 3)] =
        make_float4(-si0 * LOG2E, 2.0f * mn0 * si0 * LOG2E,
                    -si1 * LOG2E, 2.0f * mn1 * si1 * LOG2E);
    if (l == 0) cout[k] = (log_alpha[k] - 0.5f * lss - mt) * LOG2E;
}

__device__ __forceinline__ float4 fmax4(float4 a, float4 b) {
    return make_float4(fmaxf(a.x, b.x), fmaxf(a.y, b.y),
                       fmaxf(a.z, b.z), fmaxf(a.w, b.w));
}
__device__ __forceinline__ float4 add4(float4 a, float4 b) {
    return make_float4(a.x + b.x, a.y + b.y, a.z + b.z, a.w + b.w);
}
__device__ __forceinline__ float4 sq4(float4 a) {
    return make_float4(a.x * a.x, a.y * a.y, a.z * a.z, a.w * a.w);
}

// Main v3: 1024 threads = 16 waves, 256-n window. Wave g owns k in [4g,4g+4)
// -> acc[4][4] = 16 VGPRs, W per dh = 16 floats = ONE s_load_dwordx16 (32
// W-SGPRs for the dh-pair; 64-SGPR dbuf would risk the 102-SGPR cliff).
// dh unrolled x2: one lgkmcnt(0) per 144 VALU instrs. x software-pipelined
// one unrolled iteration ahead (explicit rotation, select-guarded tail) —
// round-1 showed VGPR_Count=32 (allocator over-squeeze) leaving MLP=1 and
// 38% VALU idle. waves_per_eu(8,8) pins the 64-VGPR / 8-waves-per-EU budget:
// live set = acc16 + xcur16 + xnext16 + t8 + addr ~6 = ~62.
__global__ __launch_bounds__(1024)
__attribute__((amdgpu_waves_per_eu(8, 8)))
void gmm_main(const float* __restrict__ x,
              const float4* __restrict__ w,
              const float* __restrict__ cks,
              float* __restrict__ out) {
    __shared__ float sRed[16][256];    // cross-wave softmax buffer (16 KB)

    const int tid = threadIdx.x;
    const int g = __builtin_amdgcn_readfirstlane(tid >> 6);  // wave id 0..15
    const int l = tid & 63;
    const int b = blockIdx.y;
    const int nloc = 4 * l;                       // lane's n offset in window
    const size_t nbase = (size_t)blockIdx.x * 256 + nloc;

    // init acc with the per-k constant (folds the epilogue add)
    float acc[4][4];
    #pragma unroll
    for (int k = 0; k < 4; ++k) {
        const float c = cks[g * 4 + k];
        #pragma unroll
        for (int j = 0; j < 4; ++j) acc[k][j] = c;
    }

    const float* xp = x + (size_t)b * Dn * Nn + nbase;
    const float* const xsafe = xp;                // dummy valid addr for tail
    const char* wp = (const char*)w + (size_t)g * 4096;  // g-slice: 64dh*4k*16B

    // prologue: load dh=0,1
    float4 xa0 = *(const float4*)(xp);
    float4 xb0 = *(const float4*)(xp + Nn);
    float4 xa1 = *(const float4*)(xp + 2 * Nn);
    float4 xb1 = *(const float4*)(xp + 3 * Nn);
    xp += 4 * Nn;

    #pragma unroll 1
    for (int dh = 0; dh < Dn / 2; dh += 2) {
        // 32 floats of W for (g, dh..dh+1) into SGPRs: 2 x 4k x {wx0,wy0,wx1,wy1}
        f32x16 w0, w1;
        asm("s_load_dwordx16 %0, %2, 0x0\n\t"
            "s_load_dwordx16 %1, %2, 0x40\n\t"
            "s_waitcnt lgkmcnt(0)"
            : "=&s"(w0), "=&s"(w1)
            : "s"(wp));
        wp += 128;

        // prefetch next dh-pair (unconditional loads; tail reads a safe addr)
        const float* xq = (dh < Dn / 2 - 2) ? xp : xsafe;
        const float4 na0 = *(const float4*)(xq);
        const float4 nb0 = *(const float4*)(xq + Nn);
        const float4 na1 = *(const float4*)(xq + 2 * Nn);
        const float4 nb1 = *(const float4*)(xq + 3 * Nn);
        xp += 4 * Nn;

#define GMM_K(WV, KK, A, TA, XA, TB, XB)                                  \
        {                                                                 \
            const float wx0 = WV[4 * KK + 0], wy0 = WV[4 * KK + 1];       \
            const float wx1 = WV[4 * KK + 2], wy1 = WV[4 * KK + 3];       \
            A[0] = fmaf(wx0, TA.x, A[0]); A[0] = fmaf(wy0, XA.x, A[0]);   \
            A[0] = fmaf(wx1, TB.x, A[0]); A[0] = fmaf(wy1, XB.x, A[0]);   \
            A[1] = fmaf(wx0, TA.y, A[1]); A[1] = fmaf(wy0, XA.y, A[1]);   \
            A[1] = fmaf(wx1, TB.y, A[1]); A[1] = fmaf(wy1, XB.y, A[1]);   \
            A[2] = fmaf(wx0, TA.z, A[2]); A[2] = fmaf(wy0, XA.z, A[2]);   \
            A[2] = fmaf(wx1, TB.z, A[2]); A[2] = fmaf(wy1, XB.z, A[2]);   \
            A[3] = fmaf(wx0, TA.w, A[3]); A[3] = fmaf(wy0, XA.w, A[3]);   \
            A[3] = fmaf(wx1, TB.w, A[3]); A[3] = fmaf(wy1, XB.w, A[3]);   \
        }

        {   // dh (even): xa0/xb0 with w0
            const float4 ta = sq4(xa0), tb = sq4(xb0);
            GMM_K(w0, 0, acc[0], ta, xa0, tb, xb0);
            GMM_K(w0, 1, acc[1], ta, xa0, tb, xb0);
            GMM_K(w0, 2, acc[2], ta, xa0, tb, xb0);
            GMM_K(w0, 3, acc[3], ta, xa0, tb, xb0);
        }
        {   // dh+1 (odd): xa1/xb1 with w1
            const float4 ta = sq4(xa1), tb = sq4(xb1);
            GMM_K(w1, 0, acc[0], ta, xa1, tb, xb1);
            GMM_K(w1, 1, acc[1], ta, xa1, tb, xb1);
            GMM_K(w1, 2, acc[2], ta, xa1, tb, xb1);
            GMM_K(w1, 3, acc[3], ta, xa1, tb, xb1);
        }
#undef GMM_K
        // rotate prefetched registers
        xa0 = na0; xb0 = nb0; xa1 = na1; xb1 = nb1;
    }

    // ---- softmax: cross-wave max over all 64 k (16 groups) ----
    float4 m = make_float4(acc[0][0], acc[0][1], acc[0][2], acc[0][3]);
    #pragma unroll
    for (int k = 1; k < 4; ++k)
        m = fmax4(m, make_float4(acc[k][0], acc[k][1], acc[k][2], acc[k][3]));
    *(float4*)&sRed[g][nloc] = m;
    __syncthreads();
    #pragma unroll
    for (int gg = 0; gg < 16; ++gg)
        m = fmax4(m, *(const float4*)&sRed[gg][nloc]);
    __syncthreads();   // before reusing sRed for sums

    // ---- exp2 + cross-wave sum ----
    float4 s = make_float4(0.f, 0.f, 0.f, 0.f);
    #pragma unroll
    for (int k = 0; k < 4; ++k) {
        acc[k][0] = __builtin_amdgcn_exp2f(acc[k][0] - m.x); s.x += acc[k][0];
        acc[k][1] = __builtin_amdgcn_exp2f(acc[k][1] - m.y); s.y += acc[k][1];
        acc[k][2] = __builtin_amdgcn_exp2f(acc[k][2] - m.z); s.z += acc[k][2];
        acc[k][3] = __builtin_amdgcn_exp2f(acc[k][3] - m.w); s.w += acc[k][3];
    }
    *(float4*)&sRed[g][nloc] = s;
    __syncthreads();
    s = make_float4(0.f, 0.f, 0.f, 0.f);
    #pragma unroll
    for (int gg = 0; gg < 16; ++gg)
        s = add4(s, *(const float4*)&sRed[gg][nloc]);
    const float4 r = make_float4(1.0f / s.x, 1.0f / s.y, 1.0f / s.z, 1.0f / s.w);

    // ---- store: out[b][k][n], one float4 per k, coalesced ----
    float* op = out + (size_t)(b * Kn + g * 4) * Nn + nbase;
    #pragma unroll
    for (int k = 0; k < 4; ++k) {
        *(float4*)op = make_float4(acc[k][0] * r.x, acc[k][1] * r.y,
                                   acc[k][2] * r.z, acc[k][3] * r.w);
        op += Nn;
    }
}

extern "C" void kernel_launch(void* const* d_in, const int* in_sizes, int n_in,
                              void* d_out, int out_size, void* d_ws, size_t ws_size,
                              hipStream_t stream) {
    const float* x  = (const float*)d_in[0];
    const float* mu = (const float*)d_in[1];
    const float* ls = (const float*)d_in[2];
    const float* la = (const float*)d_in[3];
    float* out = (float*)d_out;

    float4* wbuf = (float4*)d_ws;
    float*  cbuf = (float*)((char*)d_ws + (size_t)Kn * (Dn / 2) * sizeof(float4));

    gmm_prep<<<dim3(Kn), dim3(64), 0, stream>>>(mu, ls, la, wbuf, cbuf);
    gmm_main<<<dim3(Nn / 256, Bn), dim3(1024), 0, stream>>>(x, wbuf, cbuf, out);
}

// Round 3
// 264.663 us; speedup vs baseline: 1.0029x; 1.0029x over previous
//
#include <hip/hip_runtime.h>

#define LOG2E 1.4426950408889634f

constexpr int Dn = 128;
constexpr int Nn = 16384;
constexpr int Kn = 64;
constexpr int Bn = 16;

typedef float v2f  __attribute__((ext_vector_type(2)));
typedef float v16f __attribute__((ext_vector_type(16)));

__device__ __forceinline__ v2f splat2(float v) { v2f r; r[0] = v; r[1] = v; return r; }

// Prep: folds mu-normalize, exp(-log_sigma), factor -2, k-constant and log2e.
// Layout v4 (k-pair packed for v_pk_fma_f32): per (g = k>>3, d) a 16-float
// record:  [a(2p), a(2p+1), b(2p), b(2p+1)] for p = 0..3  (k = 8g + 2p + h).
// One s_load_dwordx16 per (g,d); a/b pairs land on even-aligned SGPR pairs.
__global__ __launch_bounds__(64) void gmm_prep(const float* __restrict__ mu,
                                               const float* __restrict__ log_sigma,
                                               const float* __restrict__ log_alpha,
                                               float* __restrict__ wout,
                                               float* __restrict__ cout) {
    const int k = blockIdx.x;
    const int l = threadIdx.x;        // l == dh, covers d0=2l, d0+1
    const int d0 = 2 * l;
    float m0 = mu[k * Dn + d0];
    float m1 = mu[k * Dn + d0 + 1];
    float s0 = log_sigma[k * Dn + d0];
    float s1 = log_sigma[k * Dn + d0 + 1];
    float nrm2 = m0 * m0 + m1 * m1;
    float lss = s0 + s1;
    #pragma unroll
    for (int off = 32; off > 0; off >>= 1) {
        nrm2 += __shfl_xor(nrm2, off);
        lss  += __shfl_xor(lss, off);
    }
    const float inv_nrm = 1.0f / fmaxf(sqrtf(nrm2), 1e-12f);
    const float mn0 = m0 * inv_nrm, mn1 = m1 * inv_nrm;
    const float si0 = expf(-s0), si1 = expf(-s1);
    float mt = mn0 * mn0 * si0 + mn1 * mn1 * si1;
    #pragma unroll
    for (int off = 32; off > 0; off >>= 1) mt += __shfl_xor(mt, off);

    const int gk = k >> 3;
    const int p  = (k & 7) >> 1;
    const int h  = k & 1;
    float* wg = wout + (size_t)(gk * Dn + d0) * 16;
    wg[p * 4 + h]          = -si0 * LOG2E;                 // a at d0
    wg[p * 4 + 2 + h]      = 2.0f * mn0 * si0 * LOG2E;     // b at d0
    wg[16 + p * 4 + h]     = -si1 * LOG2E;                 // a at d0+1
    wg[16 + p * 4 + 2 + h] = 2.0f * mn1 * si1 * LOG2E;     // b at d0+1
    if (l == 0) cout[k] = (log_alpha[k] - 0.5f * lss - mt) * LOG2E;
}

__device__ __forceinline__ float4 fmax4(float4 a, float4 b) {
    return make_float4(fmaxf(a.x, b.x), fmaxf(a.y, b.y),
                       fmaxf(a.z, b.z), fmaxf(a.w, b.w));
}
__device__ __forceinline__ float4 add4(float4 a, float4 b) {
    return make_float4(a.x + b.x, a.y + b.y, a.z + b.z, a.w + b.w);
}

// Main v4: 512 threads = 8 waves, 256-n window. Fixes the real round-1/2
// bottleneck: all waves re-reading the same x from L1 (~128KB L1 traffic per
// CU per dh-pair vs ~64B/cyc delivery = the 62-66% VALUBusy cap). x is now
// staged ONCE into LDS (global_load_lds w16, double-buffered 16-row slabs);
// each wave does one ds_read_b128 per d. Compute uses v_pk_fma_f32 (2
// FMA/lane/instr — the only way to the 157TF fp32 spec): k-pair packing so
// the weight operand is a natural even-aligned SGPR pair from
// s_load_dwordx16; x/t are splat via op_sel. acc = 8k x 4n = 32 VGPRs,
// ~56 live -> 8 waves/EU; LDS 40KB -> 4 blocks/CU = 32 waves/CU.
__global__ __launch_bounds__(512)
__attribute__((amdgpu_waves_per_eu(8, 8)))
void gmm_main(const float* __restrict__ x,
              const float* __restrict__ w,
              const float* __restrict__ cks,
              float* __restrict__ out) {
    constexpr int SLAB = 16;
    __shared__ float sX[2][SLAB][256];   // 32 KB double-buffered x slabs
    __shared__ float sRed[8][256];       // 8 KB cross-wave softmax buffer

    const int tid = threadIdx.x;
    const int g = __builtin_amdgcn_readfirstlane(tid >> 6);  // wave id 0..7
    const int l = tid & 63;
    const int b = blockIdx.y;
    const int nloc = 4 * l;
    const int nwin = blockIdx.x * 256;

    const float* xwin = x + (size_t)b * Dn * Nn + nwin;

    // init acc with per-k constants (folds epilogue add); lo=k(8g+2p), hi=+1
    v2f acc[4][4];
    #pragma unroll
    for (int p = 0; p < 4; ++p) {
        v2f c2; c2[0] = cks[g * 8 + 2 * p]; c2[1] = cks[g * 8 + 2 * p + 1];
        #pragma unroll
        for (int j = 0; j < 4; ++j) acc[j][p] = c2;
    }

    // wave g stages rows {2g, 2g+1} of each 16-row slab (1KB per row)
    auto stage = [&](int s) {
        #pragma unroll
        for (int rr = 0; rr < 2; ++rr) {
            const int r = 2 * g + rr;
            const float* gsrc = xwin + (size_t)(s * SLAB + r) * Nn + 4 * l;
            __builtin_amdgcn_global_load_lds(
                (const __attribute__((address_space(1))) float*)gsrc,
                (__attribute__((address_space(3))) float*)&sX[s & 1][r][0],
                16, 0, 0);
        }
    };

    stage(0);
    const char* wp = (const char*)w + (size_t)g * (Dn * 64);  // g-slice 8KB
    __syncthreads();

    #pragma unroll 1
    for (int s = 0; s < Dn / SLAB; ++s) {
        if (s + 1 < Dn / SLAB) stage(s + 1);   // fire-and-forget prefetch
        const float* xs = &sX[s & 1][0][nloc];
        #pragma unroll
        for (int r = 0; r < SLAB; ++r) {
            const float4 xv = *(const float4*)(xs + r * 256);        // ds_read_b128
            const v16f wv = *(const v16f*)(wp + (s * SLAB + r) * 64); // s_load_x16
            const float tx = xv.x * xv.x, ty = xv.y * xv.y;
            const float tz = xv.z * xv.z, tw = xv.w * xv.w;
            #pragma unroll
            for (int p = 0; p < 4; ++p) {
                v2f wa; wa[0] = wv[4 * p];     wa[1] = wv[4 * p + 1];
                v2f wb; wb[0] = wv[4 * p + 2]; wb[1] = wv[4 * p + 3];
                acc[0][p] = __builtin_elementwise_fma(wa, splat2(tx),   acc[0][p]);
                acc[0][p] = __builtin_elementwise_fma(wb, splat2(xv.x), acc[0][p]);
                acc[1][p] = __builtin_elementwise_fma(wa, splat2(ty),   acc[1][p]);
                acc[1][p] = __builtin_elementwise_fma(wb, splat2(xv.y), acc[1][p]);
                acc[2][p] = __builtin_elementwise_fma(wa, splat2(tz),   acc[2][p]);
                acc[2][p] = __builtin_elementwise_fma(wb, splat2(xv.z), acc[2][p]);
                acc[3][p] = __builtin_elementwise_fma(wa, splat2(tw),   acc[3][p]);
                acc[3][p] = __builtin_elementwise_fma(wb, splat2(xv.w), acc[3][p]);
            }
        }
        __syncthreads();   // drains the slab prefetch (vmcnt) + buffer swap
    }

    // ---- softmax: per-wave max over its 8 k, then cross-wave over 8 ----
    float4 m;
    {
        #pragma unroll
        for (int j = 0; j < 1; ++j) {}  // (keep structure flat)
        v2f m20 = __builtin_elementwise_max(acc[0][0], acc[0][1]);
        v2f q0  = __builtin_elementwise_max(acc[0][2], acc[0][3]);
        m20 = __builtin_elementwise_max(m20, q0);
        v2f m21 = __builtin_elementwise_max(acc[1][0], acc[1][1]);
        v2f q1  = __builtin_elementwise_max(acc[1][2], acc[1][3]);
        m21 = __builtin_elementwise_max(m21, q1);
        v2f m22 = __builtin_elementwise_max(acc[2][0], acc[2][1]);
        v2f q2  = __builtin_elementwise_max(acc[2][2], acc[2][3]);
        m22 = __builtin_elementwise_max(m22, q2);
        v2f m23 = __builtin_elementwise_max(acc[3][0], acc[3][1]);
        v2f q3  = __builtin_elementwise_max(acc[3][2], acc[3][3]);
        m23 = __builtin_elementwise_max(m23, q3);
        m = make_float4(fmaxf(m20[0], m20[1]), fmaxf(m21[0], m21[1]),
                        fmaxf(m22[0], m22[1]), fmaxf(m23[0], m23[1]));
    }
    *(float4*)&sRed[g][nloc] = m;
    __syncthreads();
    #pragma unroll
    for (int gg = 0; gg < 8; ++gg)
        m = fmax4(m, *(const float4*)&sRed[gg][nloc]);
    __syncthreads();   // before reusing sRed for sums

    // ---- exp2 + cross-wave sum ----
    float4 s4 = make_float4(0.f, 0.f, 0.f, 0.f);
    #pragma unroll
    for (int p = 0; p < 4; ++p) {
        acc[0][p][0] = __builtin_amdgcn_exp2f(acc[0][p][0] - m.x); s4.x += acc[0][p][0];
        acc[0][p][1] = __builtin_amdgcn_exp2f(acc[0][p][1] - m.x); s4.x += acc[0][p][1];
        acc[1][p][0] = __builtin_amdgcn_exp2f(acc[1][p][0] - m.y); s4.y += acc[1][p][0];
        acc[1][p][1] = __builtin_amdgcn_exp2f(acc[1][p][1] - m.y); s4.y += acc[1][p][1];
        acc[2][p][0] = __builtin_amdgcn_exp2f(acc[2][p][0] - m.z); s4.z += acc[2][p][0];
        acc[2][p][1] = __builtin_amdgcn_exp2f(acc[2][p][1] - m.z); s4.z += acc[2][p][1];
        acc[3][p][0] = __builtin_amdgcn_exp2f(acc[3][p][0] - m.w); s4.w += acc[3][p][0];
        acc[3][p][1] = __builtin_amdgcn_exp2f(acc[3][p][1] - m.w); s4.w += acc[3][p][1];
    }
    *(float4*)&sRed[g][nloc] = s4;
    __syncthreads();
    s4 = make_float4(0.f, 0.f, 0.f, 0.f);
    #pragma unroll
    for (int gg = 0; gg < 8; ++gg)
        s4 = add4(s4, *(const float4*)&sRed[gg][nloc]);
    const float4 r4 = make_float4(1.0f / s4.x, 1.0f / s4.y, 1.0f / s4.z, 1.0f / s4.w);

    // ---- store: out[b][k][n], k = 8g + 2p + h, one float4 per k ----
    float* op = out + (size_t)(b * Kn + g * 8) * Nn + nwin + nloc;
    #pragma unroll
    for (int p = 0; p < 4; ++p) {
        #pragma unroll
        for (int h = 0; h < 2; ++h) {
            *(float4*)op = make_float4(acc[0][p][h] * r4.x, acc[1][p][h] * r4.y,
                                       acc[2][p][h] * r4.z, acc[3][p][h] * r4.w);
            op += Nn;
        }
    }
}

extern "C" void kernel_launch(void* const* d_in, const int* in_sizes, int n_in,
                              void* d_out, int out_size, void* d_ws, size_t ws_size,
                              hipStream_t stream) {
    const float* x  = (const float*)d_in[0];
    const float* mu = (const float*)d_in[1];
    const float* ls = (const float*)d_in[2];
    const float* la = (const float*)d_in[3];
    float* out = (float*)d_out;

    float* wbuf = (float*)d_ws;                               // 64 KB
    float* cbuf = (float*)((char*)d_ws + (size_t)8 * Dn * 16 * sizeof(float));

    gmm_prep<<<dim3(Kn), dim3(64), 0, stream>>>(mu, ls, la, wbuf, cbuf);
    gmm_main<<<dim3(Nn / 256, Bn), dim3(512), 0, stream>>>(x, wbuf, cbuf, out);
}